// Round 7
// baseline (224.319 us; speedup 1.0000x reference)
//
#include <hip/hip_runtime.h>

// Problem constants (from reference setup_inputs)
constexpr int N = 16, H = 768, W = 768;
constexpr int HW = H * W;
constexpr float EPS2 = 1.0e-6f;           // EPS^2, EPS = 0.001
constexpr float INV_W1 = 1.0f / (float)(W - 1);
constexpr float INV_H1 = 1.0f / (float)(H - 1);
constexpr float WM1 = (float)(W - 1);
constexpr float HM1 = (float)(H - 1);
constexpr float WM2 = (float)(W - 2);

// LDS tile: output 64 cols x 8 rows per block; halo 8 cols, 4 rows up / 5 down.
// C_HALO=8 keeps tc0 16B-aligned (bx0%64==0) so staging float4s are aligned.
// Layout: interleaved {fx,fy} float2 per pixel -> pair gather = ds_read2_b64.
constexpr int TILE_COLS = 80;              // staged cols: [bx0-8, bx0+72)
constexpr int TILE_ROWS = 17;              // staged rows: [by0-4, by0+13)
constexpr int C_HALO = 8;
constexpr int R_HALO = 4;
constexpr int LSTRIDE = TILE_COLS;         // pixels per tile row
constexpr int TILE_FLOATS = TILE_ROWS * LSTRIDE * 2;  // 2720 floats per tensor
// LDS = 2*2720*4 = 21760 B -> 7 blocks/CU -> 28 waves/CU (87.5% cap)
constexpr int NBLK_X = W / 64, NBLK_Y = H / 8;        // 12, 96
constexpr int NBLOCKS = NBLK_X * NBLK_Y * N;          // 18432

// 8-byte vector with 4-byte alignment promise (for planar global fallback)
typedef float float2a __attribute__((ext_vector_type(2), aligned(4)));

struct DirMeta { float gx, gy; int xb, y0, y1; };  // clamped pair base / rows

__device__ __forceinline__ void dir_meta(float fx, float fy, float xf, float yf, DirMeta& m) {
    m.gx = xf + fx;
    m.gy = yf + fy;
    float x0f = floorf(m.gx);
    float y0f = floorf(m.gy);
    m.xb = (int)fminf(fmaxf(x0f, 0.0f), WM2);          // med3: pair cols {xb, xb+1}
    m.y0 = (int)fminf(fmaxf(y0f, 0.0f), HM1);
    m.y1 = (int)fminf(fmaxf(y0f + 1.0f, 0.0f), HM1);
}

// ---------- fast path ------------------------------------------------------
// Quads: u0={fx,fy}@(y0,xb), v0=@(y0,xb+1), u1=@(y1,xb), v1=@(y1,xb+1).
// Eligible iff outer floor in [0,W-2]x[0,H-2] AND all 4 inner sample coords
// in-bounds (then every mask==1 and bilinear of the linear grid is identity).
// Bounds folded as min/max trees over the raw flow values (+1 col/row shifts).
__device__ __forceinline__ bool fast_ok(const DirMeta& m,
                                        float2 u0, float2 v0, float2 u1, float2 v1) {
    float x0f = floorf(m.gx), y0f = floorf(m.gy);
    // x-samples rel x0f: {u0.x, v0.x+1, u1.x, v1.x+1}
    float a = v0.x + 1.0f, b = v1.x + 1.0f;
    float xmn = fminf(fminf(u0.x, u1.x), fminf(a, b));
    float xmx = fmaxf(fmaxf(u0.x, u1.x), fmaxf(a, b));
    // y-samples rel y0f: {u0.y, v0.y, u1.y+1, v1.y+1}
    float c = u1.y + 1.0f, d = v1.y + 1.0f;
    float ymn = fminf(fminf(u0.y, v0.y), fminf(c, d));
    float ymx = fmaxf(fmaxf(u0.y, v0.y), fmaxf(c, d));
    return (x0f >= 0.0f) & (x0f <= WM2) & (y0f >= 0.0f) & (y0f <= HM1 - 1.0f)
         & (x0f + xmn >= 0.0f) & (x0f + xmx <= WM1)
         & (y0f + ymn >= 0.0f) & (y0f + ymx <= HM1);
}

// All-valid residual, paired component math (pk-fusable):
// fv = bilerp(flow1), diff = sqrt(((fxc+fv.x)/(W-1))^2 + ((fyc+fv.y)/(H-1))^2 + eps^2)
__device__ __forceinline__ float fast_eval(const DirMeta& m,
                                           float2 u0, float2 v0, float2 u1, float2 v1,
                                           float fxc, float fyc) {
    float x0f = floorf(m.gx), y0f = floorf(m.gy);   // CSE'd with fast_ok
    float wx1 = m.gx - x0f, wy1 = m.gy - y0f;
    float ftx = fmaf(wx1, v0.x - u0.x, u0.x);
    float fty = fmaf(wx1, v0.y - u0.y, u0.y);
    float fbx = fmaf(wx1, v1.x - u1.x, u1.x);
    float fby = fmaf(wx1, v1.y - u1.y, u1.y);
    float fvx = fmaf(wy1, fbx - ftx, ftx);
    float fvy = fmaf(wy1, fby - fty, fty);
    float a = (fxc + fvx) * INV_W1;
    float b = (fyc + fvy) * INV_H1;
    return sqrtf(fmaf(a, a, fmaf(b, b, EPS2)));
}

// ---------- general (border / wild-flow) path (verified rounds 4-6) --------
__device__ __forceinline__ float2 wg(float fx, float fy, float xi, float yi) {
    float gx = xi + fx, gy = yi + fy;
    float x0 = floorf(gx), y0 = floorf(gy);
    float wx1 = gx - x0, wx0 = 1.0f - wx1;
    float wy1 = gy - y0, wy0 = 1.0f - wy1;
    float vx0 = (x0 >= 0.0f  && x0 <= WM1)        ? 1.0f : 0.0f;
    float vx1 = (x0 >= -1.0f && x0 <= WM1 - 1.0f) ? 1.0f : 0.0f;
    float vy0 = (y0 >= 0.0f  && y0 <= HM1)        ? 1.0f : 0.0f;
    float vy1 = (y0 >= -1.0f && y0 <= HM1 - 1.0f) ? 1.0f : 0.0f;
    float ax = wx0 * vx0, bx = wx1 * vx1, sx = ax + bx;
    float ay = wy0 * vy0, by = wy1 * vy1, sy = ay + by;
    float ms = sx * sy;
    float kx = (ms >= 0.9999f) ? INV_W1 : 0.0f;
    float ky = (ms >= 0.9999f) ? INV_H1 : 0.0f;
    float2 r;
    r.x = fmaf(sx, x0, bx) * sy * kx;
    r.y = fmaf(sy, y0, by) * sx * ky;
    return r;
}

__device__ __forceinline__ float dir_eval(const DirMeta& m,
                                          float2 u0, float2 v0, float2 u1, float2 v1,
                                          int x, int y) {
    float x0f = floorf(m.gx), y0f = floorf(m.gy);
    float wx1 = m.gx - x0f, wx0 = 1.0f - wx1;
    float wy1 = m.gy - y0f, wy0 = 1.0f - wy1;
    float x1f = x0f + 1.0f, y1f = y0f + 1.0f;
    float vx0 = (x0f >= 0.0f && x0f <= WM1) ? 1.0f : 0.0f;
    float vx1 = (x1f >= 0.0f && x1f <= WM1) ? 1.0f : 0.0f;
    float vy0 = (y0f >= 0.0f && y0f <= HM1) ? 1.0f : 0.0f;
    float vy1 = (y1f >= 0.0f && y1f <= HM1) ? 1.0f : 0.0f;
    float axw = wx0 * vx0, bxw = wx1 * vx1;
    float ayw = wy0 * vy0, byw = wy1 * vy1;
    float sxw = axw + bxw, syw = ayw + byw;
    float msum = sxw * syw;

    // gathered pair is at base xb = clamp(x0,0,W-2): select col within pair
    bool selA = (x0f >= WM1);
    bool selB = (x0f >= 0.0f);
    float fx00 = selA ? v0.x : u0.x;
    float fx01 = selB ? v0.x : u0.x;
    float fy00 = selA ? v0.y : u0.y;
    float fy01 = selB ? v0.y : u0.y;
    float fx10 = selA ? v1.x : u1.x;
    float fx11 = selB ? v1.x : u1.x;
    float fy10 = selA ? v1.y : u1.y;
    float fy11 = selB ? v1.y : u1.y;

    float x0c = fminf(fmaxf(x0f, 0.0f), WM1);
    float x1c = fminf(fmaxf(x1f, 0.0f), WM1);
    float y0c = fminf(fmaxf(y0f, 0.0f), HM1);
    float y1c = fminf(fmaxf(y1f, 0.0f), HM1);

    float2 m00 = wg(fx00, fy00, x0c, y0c);
    float2 m01 = wg(fx01, fy01, x1c, y0c);
    float2 m10 = wg(fx10, fy10, x0c, y1c);
    float2 m11 = wg(fx11, fy11, x1c, y1c);

    float w00 = axw * ayw, w10 = bxw * ayw, w01 = axw * byw, w11 = bxw * byw;
    float mx = w00 * m00.x + w10 * m01.x + w01 * m10.x + w11 * m11.x;
    float my = w00 * m00.y + w10 * m01.y + w01 * m10.y + w11 * m11.y;
    float keep = (msum >= 0.9999f) ? 1.0f : 0.0f;
    mx *= keep; my *= keep;

    float dx = (float)x * INV_W1 - mx;
    float dy = (float)y * INV_H1 - my;
    return sqrtf(fmaf(dx, dx, fmaf(dy, dy, EPS2)));
}

// Load the pixel pair (pix, pix+1) from an interleaved tile as two float2s.
// Two adjacent 8B loads at one base -> fuses to ds_read2_b64. No shuffles.
__device__ __forceinline__ void ld_quad(const float* t, int pix, float2& u, float2& v) {
    u = *(const float2*)(t + 2 * pix);
    v = *(const float2*)(t + 2 * pix + 2);
}

__global__ __launch_bounds__(256, 7)
void cycle_loss_kernel(const float* __restrict__ A,   // UV_AtoB
                       const float* __restrict__ B,   // UV_BtoA
                       float* __restrict__ ws,
                       float* __restrict__ out,
                       int use_ws) {
    __shared__ float lds[2 * TILE_FLOATS];   // [0]=A tile, [TILE_FLOATS]=B tile
    __shared__ float wsum[4];

    int tid  = threadIdx.x;
    int lane = tid & 63;
    int wv   = tid >> 6;
    int bx0 = blockIdx.x * 64;
    int by0 = blockIdx.y * 8;
    int b   = blockIdx.z;
    const float* Ab = A + (size_t)b * 2 * HW;
    const float* Bb = B + (size_t)b * 2 * HW;
    int tc0 = bx0 - C_HALO;    // 16B-aligned (bx0%64==0, C_HALO=8)
    int tr0 = by0 - R_HALO;

    // ---- stage both tensors as interleaved {fx,fy} tiles -----------------
    // 680 tasks: tensor(2) x row(17) x float4-col-chunk(20). Each task: two
    // coalesced global float4 loads (fx,fy planes) -> two 16B LDS writes.
    // Chunks 4-col aligned & W%4==0 -> whole chunk in- or out-of-image;
    // out-of-image cells stay unwritten and are provably never read
    // (eligible reads use image-clamped coords inside the tile).
    constexpr int ROW_CHUNKS = TILE_COLS / 4;          // 20
    constexpr int TASKS_PER_T = TILE_ROWS * ROW_CHUNKS; // 340
    for (int i = tid; i < 2 * TASKS_PER_T; i += 256) {
        int t   = i / TASKS_PER_T;
        int rem = i - t * TASKS_PER_T;
        int lr  = rem / ROW_CHUNKS;
        int lc4 = rem - lr * ROW_CHUNKS;
        int rg = tr0 + lr;
        int cg = tc0 + lc4 * 4;
        if ((unsigned)rg < (unsigned)H && (unsigned)cg < (unsigned)W) {
            const float* src = (t ? Bb : Ab) + rg * W + cg;
            float4 fx = *(const float4*)(src);
            float4 fy = *(const float4*)(src + HW);
            float* dst = &lds[t * TILE_FLOATS + (lr * LSTRIDE + lc4 * 4) * 2];
            *(float4*)(dst)     = make_float4(fx.x, fy.x, fx.y, fy.y);
            *(float4*)(dst + 4) = make_float4(fx.z, fy.z, fx.w, fy.w);
        }
    }
    __syncthreads();

    const float* ldsA = lds;
    const float* ldsB = lds + TILE_FLOATS;
    int x  = bx0 + lane;
    int yb = by0 + wv * 2;        // 2 consecutive rows per thread
    int lxc = lane + C_HALO;
    float xf = (float)x;

    // centers: one conflict-light ds_read_b64 per tensor per pixel
    float2 aC[2], bC[2];
    #pragma unroll
    for (int p = 0; p < 2; ++p) {
        int co = (wv * 2 + p + R_HALO) * LSTRIDE + lxc;
        aC[p] = *(const float2*)(ldsA + 2 * co);
        bC[p] = *(const float2*)(ldsB + 2 * co);
    }

    float s = 0.0f;
    #pragma unroll
    for (int p = 0; p < 2; ++p) {
        int y = yb + p;
        float yf = (float)y;
        DirMeta m1, m2;
        dir_meta(bC[p].x, bC[p].y, xf, yf, m1);   // ABA: outer flow B, gather A
        dir_meta(aC[p].x, aC[p].y, xf, yf, m2);   // BAB: outer flow A, gather B

        // tile-local coords + eligibility (unsigned trick)
        int x1l = m1.xb - tc0, y1l0 = m1.y0 - tr0, y1l1 = m1.y1 - tr0;
        int x2l = m2.xb - tc0, y2l0 = m2.y0 - tr0, y2l1 = m2.y1 - tr0;
        bool e1 = ((unsigned)x1l <= (unsigned)(TILE_COLS - 2))
                & ((unsigned)y1l0 < (unsigned)TILE_ROWS)
                & ((unsigned)y1l1 < (unsigned)TILE_ROWS);
        bool e2 = ((unsigned)x2l <= (unsigned)(TILE_COLS - 2))
                & ((unsigned)y2l0 < (unsigned)TILE_ROWS)
                & ((unsigned)y2l1 < (unsigned)TILE_ROWS);

        float2 u10, v10, u11, v11, u20, v20, u21, v21;
        if (__all(e1 & e2)) {
            // 4 ds_read2_b64 total (2 per direction)
            ld_quad(ldsA, y1l0 * LSTRIDE + x1l, u10, v10);
            ld_quad(ldsA, y1l1 * LSTRIDE + x1l, u11, v11);
            ld_quad(ldsB, y2l0 * LSTRIDE + x2l, u20, v20);
            ld_quad(ldsB, y2l1 * LSTRIDE + x2l, u21, v21);
        } else {
            // rare (~1%): per-lane LDS/global select
            if (e1) {
                ld_quad(ldsA, y1l0 * LSTRIDE + x1l, u10, v10);
                ld_quad(ldsA, y1l1 * LSTRIDE + x1l, u11, v11);
            } else {
                int o0 = m1.y0 * W + m1.xb, o1 = m1.y1 * W + m1.xb;
                float2a rx0 = *(const float2a*)(Ab + o0);
                float2a ry0 = *(const float2a*)(Ab + HW + o0);
                float2a rx1 = *(const float2a*)(Ab + o1);
                float2a ry1 = *(const float2a*)(Ab + HW + o1);
                u10 = make_float2(rx0.x, ry0.x); v10 = make_float2(rx0.y, ry0.y);
                u11 = make_float2(rx1.x, ry1.x); v11 = make_float2(rx1.y, ry1.y);
            }
            if (e2) {
                ld_quad(ldsB, y2l0 * LSTRIDE + x2l, u20, v20);
                ld_quad(ldsB, y2l1 * LSTRIDE + x2l, u21, v21);
            } else {
                int o0 = m2.y0 * W + m2.xb, o1 = m2.y1 * W + m2.xb;
                float2a rx0 = *(const float2a*)(Bb + o0);
                float2a ry0 = *(const float2a*)(Bb + HW + o0);
                float2a rx1 = *(const float2a*)(Bb + o1);
                float2a ry1 = *(const float2a*)(Bb + HW + o1);
                u20 = make_float2(rx0.x, ry0.x); v20 = make_float2(rx0.y, ry0.y);
                u21 = make_float2(rx1.x, ry1.x); v21 = make_float2(rx1.y, ry1.y);
            }
        }

        bool ok = fast_ok(m1, u10, v10, u11, v11)
                & fast_ok(m2, u20, v20, u21, v21);
        if (__all(ok)) {
            s += fast_eval(m1, u10, v10, u11, v11, bC[p].x, bC[p].y);
            s += fast_eval(m2, u20, v20, u21, v21, aC[p].x, aC[p].y);
        } else {
            s += dir_eval(m1, u10, v10, u11, v11, x, y);
            s += dir_eval(m2, u20, v20, u21, v21, x, y);
        }
    }

    // wave(64) shuffle reduce -> LDS -> one value per block
    #pragma unroll
    for (int o = 32; o > 0; o >>= 1) s += __shfl_down(s, o, 64);
    if (lane == 0) wsum[wv] = s;
    __syncthreads();
    if (tid == 0) {
        float tsum = wsum[0] + wsum[1] + wsum[2] + wsum[3];
        if (use_ws) {
            int bid = (blockIdx.z * gridDim.y + blockIdx.y) * gridDim.x + blockIdx.x;
            ws[bid] = tsum;                      // plain store, no atomics
        } else {
            atomicAdd(out, tsum * (1.0f / ((float)N * (float)H * (float)W)));
        }
    }
}

__global__ __launch_bounds__(256)
void reduce_kernel(const float* __restrict__ ws, float* __restrict__ out) {
    float s = 0.0f;
    for (int i = threadIdx.x; i < NBLOCKS; i += 256) s += ws[i];  // 72 iters
    #pragma unroll
    for (int o = 32; o > 0; o >>= 1) s += __shfl_down(s, o, 64);
    __shared__ float wsum[4];
    int lane = threadIdx.x & 63, wv = threadIdx.x >> 6;
    if (lane == 0) wsum[wv] = s;
    __syncthreads();
    if (threadIdx.x == 0) {
        float t = wsum[0] + wsum[1] + wsum[2] + wsum[3];
        out[0] = t * (1.0f / ((float)N * (float)H * (float)W));
    }
}

extern "C" void kernel_launch(void* const* d_in, const int* in_sizes, int n_in,
                              void* d_out, int out_size, void* d_ws, size_t ws_size,
                              hipStream_t stream) {
    const float* A = (const float*)d_in[0];   // UV_AtoB [16,2,768,768]
    const float* B = (const float*)d_in[1];   // UV_BtoA [16,2,768,768]
    float* out = (float*)d_out;               // scalar fp32
    float* ws  = (float*)d_ws;

    int use_ws = (ws_size >= NBLOCKS * sizeof(float)) ? 1 : 0;
    if (!use_ws) hipMemsetAsync(out, 0, sizeof(float), stream);

    dim3 grid(NBLK_X, NBLK_Y, N);             // (12, 96, 16) = 18432 blocks
    cycle_loss_kernel<<<grid, 256, 0, stream>>>(A, B, ws, out, use_ws);
    if (use_ws) reduce_kernel<<<1, 256, 0, stream>>>(ws, out);
}

// Round 8
// 202.088 us; speedup vs baseline: 1.1100x; 1.1100x over previous
//
#include <hip/hip_runtime.h>

// Problem constants (from reference setup_inputs). Note W == H == 768 -> all
// x/y scales and centers coincide, so packed (x,y) math shares constants.
constexpr int N = 16, H = 768, W = 768;
constexpr int HW = H * W;
constexpr float EPS2 = 1.0e-6f;            // EPS^2, EPS = 0.001
constexpr float INV = 1.0f / 767.0f;       // 1/(W-1) == 1/(H-1)
constexpr float WM1 = 767.0f, WM2 = 766.0f, HM1 = 767.0f;
constexpr float CHALF  = 383.5f;           // (W-1)/2 : |c-383.5|<=383.5 <=> c in [0,767]
constexpr float CHALFI = 383.0f;           // (W-2)/2 : |c-383|  <=383   <=> c in [0,766]

// LDS tile geometry (round-6 sweet spot): output 64 cols x 16 rows per block,
// halo 8 cols / 4 rows. Interleaved {fx,fy} per pixel -> pair = ds_read2_b64.
constexpr int TILE_COLS = 80;              // staged cols: [bx0-8, bx0+72)
constexpr int TILE_ROWS = 24;              // staged rows: [by0-4, by0+20)
constexpr int C_HALO = 8;
constexpr int R_HALO = 4;
constexpr int LSTRIDE = TILE_COLS;
constexpr int TILE_FLOATS = TILE_ROWS * LSTRIDE * 2;  // 3840 floats per tensor
constexpr int NBLK_X = W / 64, NBLK_Y = H / 16;       // 12, 48
constexpr int NBLOCKS = NBLK_X * NBLK_Y * N;          // 9216

// packed-fp32 pair: arithmetic on this type emits v_pk_{add,mul,fma}_f32
typedef float v2f __attribute__((ext_vector_type(2)));
// 8-byte vector with 4-byte alignment promise (planar global fallback)
typedef float float2a __attribute__((ext_vector_type(2), aligned(4)));

struct DirMeta { v2f g; v2f f0; int xb, y0, y1; };

__device__ __forceinline__ void dir_meta(v2f flow, v2f xy, DirMeta& m) {
    m.g = xy + flow;                                   // 1 pk_add
    m.f0 = (v2f){floorf(m.g.x), floorf(m.g.y)};
    m.xb = (int)fminf(fmaxf(m.f0.x, 0.0f), WM2);       // med3 + cvt
    m.y0 = (int)fminf(fmaxf(m.f0.y, 0.0f), HM1);
    m.y1 = (int)fminf(fmaxf(m.f0.y + 1.0f, 0.0f), HM1); // NOT min(y0+1,..): y0f=-1 case
}

// ---------- fast path ------------------------------------------------------
// Quads: u0={fx,fy}@(y0,xb), v0=@(y0,xb+1), u1=@(y1,xb), v1=@(y1,xb+1).
// Eligible iff outer floor in [0,W-2]x[0,H-2] AND all 4 inner sample coords
// in [0,W-1]x[0,H-1] (then every validity mask is 1 and bilinear of the
// linear grid is the identity). Centered-abs form: compares use free |x|
// input modifiers; max-trees fuse to v_max3; diagonal corners pack.
__device__ __forceinline__ bool fast_ok(v2f f0, v2f u0, v2f v0, v2f u1, v2f v1) {
    v2f c  = f0 - CHALF;          // pk
    v2f c1 = c + 1.0f;            // pk
    v2f d00 = c  + u0;            // pk: corner (+0,+0)
    v2f d11 = c1 + v1;            // pk: corner (+1,+1)
    float d01x = c1.x + v0.x, d01y = c.y  + v0.y;   // corner (+1,+0)
    float d10x = c.x  + u1.x, d10y = c1.y + u1.y;   // corner (+0,+1)
    float xm = fmaxf(fabsf(d00.x), fabsf(d01x));
    xm = fmaxf(xm, fmaxf(fabsf(d10x), fabsf(d11.x)));   // v_max3
    float ym = fmaxf(fabsf(d00.y), fabsf(d01y));
    ym = fmaxf(ym, fmaxf(fabsf(d10y), fabsf(d11.y)));
    v2f t = c + 0.5f;             // pk: f0 - 383
    return (xm <= CHALF) & (ym <= CHALF)
         & (fabsf(t.x) <= CHALFI) & (fabsf(t.y) <= CHALFI);
}

// All-valid residual (bilerp of flow1, identity inner warp):
__device__ __forceinline__ float fast_eval(const DirMeta& m,
                                           v2f u0, v2f v0, v2f u1, v2f v1,
                                           v2f cen) {
    v2f w = m.g - m.f0;                       // (wx1, wy1), pk
    v2f wx = (v2f){w.x, w.x};
    v2f wy = (v2f){w.y, w.y};
    v2f ft = u0 + wx * (v0 - u0);             // pk_sub + pk_fma
    v2f fb = u1 + wx * (v1 - u1);
    v2f fv = ft + wy * (fb - ft);
    v2f r = (cen + fv) * INV;                 // pk_add + pk_mul
    return sqrtf(fmaf(r.x, r.x, fmaf(r.y, r.y, EPS2)));
}

// ---------- general (border / wild-flow) path (verified rounds 4-7) --------
__device__ __forceinline__ float2 wg(float fx, float fy, float xi, float yi) {
    float gx = xi + fx, gy = yi + fy;
    float x0 = floorf(gx), y0 = floorf(gy);
    float wx1 = gx - x0, wx0 = 1.0f - wx1;
    float wy1 = gy - y0, wy0 = 1.0f - wy1;
    float vx0 = (x0 >= 0.0f  && x0 <= WM1)        ? 1.0f : 0.0f;
    float vx1 = (x0 >= -1.0f && x0 <= WM1 - 1.0f) ? 1.0f : 0.0f;
    float vy0 = (y0 >= 0.0f  && y0 <= HM1)        ? 1.0f : 0.0f;
    float vy1 = (y0 >= -1.0f && y0 <= HM1 - 1.0f) ? 1.0f : 0.0f;
    float ax = wx0 * vx0, bx = wx1 * vx1, sx = ax + bx;
    float ay = wy0 * vy0, by = wy1 * vy1, sy = ay + by;
    float ms = sx * sy;
    float kx = (ms >= 0.9999f) ? INV : 0.0f;
    float ky = (ms >= 0.9999f) ? INV : 0.0f;
    float2 r;
    r.x = fmaf(sx, x0, bx) * sy * kx;
    r.y = fmaf(sy, y0, by) * sx * ky;
    return r;
}

__device__ __forceinline__ float dir_eval(const DirMeta& m,
                                          v2f u0, v2f v0, v2f u1, v2f v1,
                                          float xf, float yf) {
    float x0f = m.f0.x, y0f = m.f0.y;
    float wx1 = m.g.x - x0f, wx0 = 1.0f - wx1;
    float wy1 = m.g.y - y0f, wy0 = 1.0f - wy1;
    float x1f = x0f + 1.0f, y1f = y0f + 1.0f;
    float vx0 = (x0f >= 0.0f && x0f <= WM1) ? 1.0f : 0.0f;
    float vx1 = (x1f >= 0.0f && x1f <= WM1) ? 1.0f : 0.0f;
    float vy0 = (y0f >= 0.0f && y0f <= HM1) ? 1.0f : 0.0f;
    float vy1 = (y1f >= 0.0f && y1f <= HM1) ? 1.0f : 0.0f;
    float axw = wx0 * vx0, bxw = wx1 * vx1;
    float ayw = wy0 * vy0, byw = wy1 * vy1;
    float sxw = axw + bxw, syw = ayw + byw;
    float msum = sxw * syw;

    // gathered pair is at base xb = clamp(x0,0,W-2): select col within pair
    bool selA = (x0f >= WM1);
    bool selB = (x0f >= 0.0f);
    float fx00 = selA ? v0.x : u0.x;
    float fx01 = selB ? v0.x : u0.x;
    float fy00 = selA ? v0.y : u0.y;
    float fy01 = selB ? v0.y : u0.y;
    float fx10 = selA ? v1.x : u1.x;
    float fx11 = selB ? v1.x : u1.x;
    float fy10 = selA ? v1.y : u1.y;
    float fy11 = selB ? v1.y : u1.y;

    float x0c = fminf(fmaxf(x0f, 0.0f), WM1);
    float x1c = fminf(fmaxf(x1f, 0.0f), WM1);
    float y0c = fminf(fmaxf(y0f, 0.0f), HM1);
    float y1c = fminf(fmaxf(y1f, 0.0f), HM1);

    float2 m00 = wg(fx00, fy00, x0c, y0c);
    float2 m01 = wg(fx01, fy01, x1c, y0c);
    float2 m10 = wg(fx10, fy10, x0c, y1c);
    float2 m11 = wg(fx11, fy11, x1c, y1c);

    float w00 = axw * ayw, w10 = bxw * ayw, w01 = axw * byw, w11 = bxw * byw;
    float mx = w00 * m00.x + w10 * m01.x + w01 * m10.x + w11 * m11.x;
    float my = w00 * m00.y + w10 * m01.y + w01 * m10.y + w11 * m11.y;
    float keep = (msum >= 0.9999f) ? 1.0f : 0.0f;
    mx *= keep; my *= keep;

    float dx = xf * INV - mx;
    float dy = yf * INV - my;
    return sqrtf(fmaf(dx, dx, fmaf(dy, dy, EPS2)));
}

// Pixel pair (pix, pix+1) from interleaved tile: two adjacent 8B reads at one
// base -> fuses to ds_read2_b64.
__device__ __forceinline__ void ld_quad(const float* t, int pix, v2f& u, v2f& v) {
    u = *(const v2f*)(t + 2 * pix);
    v = *(const v2f*)(t + 2 * pix + 2);
}

__global__ __launch_bounds__(256)
void cycle_loss_kernel(const float* __restrict__ A,   // UV_AtoB
                       const float* __restrict__ B,   // UV_BtoA
                       float* __restrict__ ws,
                       float* __restrict__ out,
                       int use_ws) {
    __shared__ float lds[2 * TILE_FLOATS];   // [0]=A tile, [TILE_FLOATS]=B tile
    __shared__ float wsum[4];

    int tid  = threadIdx.x;
    int lane = tid & 63;
    int wv   = tid >> 6;
    int bx0 = blockIdx.x * 64;
    int by0 = blockIdx.y * 16;
    int b   = blockIdx.z;
    const float* Ab = A + (size_t)b * 2 * HW;
    const float* Bb = B + (size_t)b * 2 * HW;
    int tc0 = bx0 - C_HALO;    // 16B-aligned
    int tr0 = by0 - R_HALO;

    // ---- stage both tensors as interleaved {fx,fy} tiles (round-6) -------
    constexpr int ROW_CHUNKS = TILE_COLS / 4;            // 20
    constexpr int TASKS_PER_T = TILE_ROWS * ROW_CHUNKS;  // 480
    for (int i = tid; i < 2 * TASKS_PER_T; i += 256) {
        int t   = i / TASKS_PER_T;
        int rem = i - t * TASKS_PER_T;
        int lr  = rem / ROW_CHUNKS;
        int lc4 = rem - lr * ROW_CHUNKS;
        int rg = tr0 + lr;
        int cg = tc0 + lc4 * 4;
        if ((unsigned)rg < (unsigned)H && (unsigned)cg < (unsigned)W) {
            const float* src = (t ? Bb : Ab) + rg * W + cg;
            float4 fx = *(const float4*)(src);
            float4 fy = *(const float4*)(src + HW);
            float* dst = &lds[t * TILE_FLOATS + (lr * LSTRIDE + lc4 * 4) * 2];
            *(float4*)(dst)     = make_float4(fx.x, fy.x, fx.y, fy.y);
            *(float4*)(dst + 4) = make_float4(fx.z, fy.z, fx.w, fy.w);
        }
    }
    __syncthreads();

    const float* ldsA = lds;
    const float* ldsB = lds + TILE_FLOATS;
    int x  = bx0 + lane;
    int yb = by0 + wv * 4;        // 4 consecutive rows per thread
    int lxc = lane + C_HALO;
    float xf = (float)x;

    // centers: one ds_read_b64 per tensor per pixel (2-way aliasing = free)
    v2f aC[4], bC[4];
    #pragma unroll
    for (int p = 0; p < 4; ++p) {
        int co = (wv * 4 + p + R_HALO) * LSTRIDE + lxc;
        aC[p] = *(const v2f*)(ldsA + 2 * co);
        bC[p] = *(const v2f*)(ldsB + 2 * co);
    }

    float s = 0.0f;
    #pragma unroll
    for (int p = 0; p < 4; ++p) {
        float yf = (float)(yb + p);
        v2f xy = (v2f){xf, yf};
        DirMeta m1, m2;
        dir_meta(bC[p], xy, m1);   // ABA: outer flow B, gather A
        dir_meta(aC[p], xy, m2);   // BAB: outer flow A, gather B

        // tile-local coords + eligibility (unsigned trick)
        int x1l = m1.xb - tc0, y1l0 = m1.y0 - tr0, y1l1 = m1.y1 - tr0;
        int x2l = m2.xb - tc0, y2l0 = m2.y0 - tr0, y2l1 = m2.y1 - tr0;
        bool e1 = ((unsigned)x1l <= (unsigned)(TILE_COLS - 2))
                & ((unsigned)y1l0 < (unsigned)TILE_ROWS)
                & ((unsigned)y1l1 < (unsigned)TILE_ROWS);
        bool e2 = ((unsigned)x2l <= (unsigned)(TILE_COLS - 2))
                & ((unsigned)y2l0 < (unsigned)TILE_ROWS)
                & ((unsigned)y2l1 < (unsigned)TILE_ROWS);

        v2f u10, v10, u11, v11, u20, v20, u21, v21;
        if (__all(e1 & e2)) {
            ld_quad(ldsA, y1l0 * LSTRIDE + x1l, u10, v10);
            ld_quad(ldsA, y1l1 * LSTRIDE + x1l, u11, v11);
            ld_quad(ldsB, y2l0 * LSTRIDE + x2l, u20, v20);
            ld_quad(ldsB, y2l1 * LSTRIDE + x2l, u21, v21);
        } else {
            // rare: per-lane LDS/global select
            if (e1) {
                ld_quad(ldsA, y1l0 * LSTRIDE + x1l, u10, v10);
                ld_quad(ldsA, y1l1 * LSTRIDE + x1l, u11, v11);
            } else {
                int o0 = m1.y0 * W + m1.xb, o1 = m1.y1 * W + m1.xb;
                float2a rx0 = *(const float2a*)(Ab + o0);
                float2a ry0 = *(const float2a*)(Ab + HW + o0);
                float2a rx1 = *(const float2a*)(Ab + o1);
                float2a ry1 = *(const float2a*)(Ab + HW + o1);
                u10 = (v2f){rx0.x, ry0.x}; v10 = (v2f){rx0.y, ry0.y};
                u11 = (v2f){rx1.x, ry1.x}; v11 = (v2f){rx1.y, ry1.y};
            }
            if (e2) {
                ld_quad(ldsB, y2l0 * LSTRIDE + x2l, u20, v20);
                ld_quad(ldsB, y2l1 * LSTRIDE + x2l, u21, v21);
            } else {
                int o0 = m2.y0 * W + m2.xb, o1 = m2.y1 * W + m2.xb;
                float2a rx0 = *(const float2a*)(Bb + o0);
                float2a ry0 = *(const float2a*)(Bb + HW + o0);
                float2a rx1 = *(const float2a*)(Bb + o1);
                float2a ry1 = *(const float2a*)(Bb + HW + o1);
                u20 = (v2f){rx0.x, ry0.x}; v20 = (v2f){rx0.y, ry0.y};
                u21 = (v2f){rx1.x, ry1.x}; v21 = (v2f){rx1.y, ry1.y};
            }
        }

        bool ok = fast_ok(m1.f0, u10, v10, u11, v11)
                & fast_ok(m2.f0, u20, v20, u21, v21);
        if (__all(ok)) {
            s += fast_eval(m1, u10, v10, u11, v11, bC[p]);
            s += fast_eval(m2, u20, v20, u21, v21, aC[p]);
        } else {
            s += dir_eval(m1, u10, v10, u11, v11, xf, yf);
            s += dir_eval(m2, u20, v20, u21, v21, xf, yf);
        }
    }

    // wave(64) shuffle reduce -> LDS -> one value per block
    #pragma unroll
    for (int o = 32; o > 0; o >>= 1) s += __shfl_down(s, o, 64);
    if (lane == 0) wsum[wv] = s;
    __syncthreads();
    if (tid == 0) {
        float tsum = wsum[0] + wsum[1] + wsum[2] + wsum[3];
        if (use_ws) {
            int bid = (blockIdx.z * gridDim.y + blockIdx.y) * gridDim.x + blockIdx.x;
            ws[bid] = tsum;                      // plain store, no atomics
        } else {
            atomicAdd(out, tsum * (1.0f / ((float)N * (float)H * (float)W)));
        }
    }
}

__global__ __launch_bounds__(256)
void reduce_kernel(const float* __restrict__ ws, float* __restrict__ out) {
    float s = 0.0f;
    for (int i = threadIdx.x; i < NBLOCKS / 4; i += 256) {   // float4: 9 iters
        float4 v = *(const float4*)(ws + 4 * i);
        s += (v.x + v.y) + (v.z + v.w);
    }
    #pragma unroll
    for (int o = 32; o > 0; o >>= 1) s += __shfl_down(s, o, 64);
    __shared__ float wsum[4];
    int lane = threadIdx.x & 63, wv = threadIdx.x >> 6;
    if (lane == 0) wsum[wv] = s;
    __syncthreads();
    if (threadIdx.x == 0) {
        float t = wsum[0] + wsum[1] + wsum[2] + wsum[3];
        out[0] = t * (1.0f / ((float)N * (float)H * (float)W));
    }
}

extern "C" void kernel_launch(void* const* d_in, const int* in_sizes, int n_in,
                              void* d_out, int out_size, void* d_ws, size_t ws_size,
                              hipStream_t stream) {
    const float* A = (const float*)d_in[0];   // UV_AtoB [16,2,768,768]
    const float* B = (const float*)d_in[1];   // UV_BtoA [16,2,768,768]
    float* out = (float*)d_out;               // scalar fp32
    float* ws  = (float*)d_ws;

    int use_ws = (ws_size >= NBLOCKS * sizeof(float)) ? 1 : 0;
    if (!use_ws) hipMemsetAsync(out, 0, sizeof(float), stream);

    dim3 grid(NBLK_X, NBLK_Y, N);             // (12, 48, 16) = 9216 blocks
    cycle_loss_kernel<<<grid, 256, 0, stream>>>(A, B, ws, out, use_ws);
    if (use_ws) reduce_kernel<<<1, 256, 0, stream>>>(ws, out);
}